// Round 3
// baseline (318.227 us; speedup 1.0000x reference)
//
#include <hip/hip_runtime.h>

typedef unsigned short u16;
typedef u16 u16x4 __attribute__((ext_vector_type(4)));
typedef u16 u16x8 __attribute__((ext_vector_type(8)));
typedef __bf16 bf16;
typedef bf16 bf16x8 __attribute__((ext_vector_type(8)));
typedef float f32x4 __attribute__((ext_vector_type(4)));

__device__ __forceinline__ float bf2f(u16 v) {
  union { unsigned u; float f; } x; x.u = ((unsigned)v) << 16; return x.f;
}
__device__ __forceinline__ u16 f2bf(float f) {
  union { float f; unsigned u; } x; x.f = f;
  unsigned u = x.u;
  u += 0x7fffu + ((u >> 16) & 1u);   // RNE
  return (u16)(u >> 16);
}

// async global->LDS, 16B per lane; LDS base wave-uniform, global source per-lane (m173)
#define GLDS16(g, l) __builtin_amdgcn_global_load_lds( \
    (const __attribute__((address_space(1))) unsigned int*)(const void*)(g), \
    (__attribute__((address_space(3))) unsigned int*)(void*)(l), 16, 0, 0)

// ---------------- fused prep + downsample v3 ----------------
// grid 7680, ds blocks interleaved 1-in-10 (blk%10==0) so streaming cvt blocks
// co-reside with latency-bound ds blocks (R2's clumping killed the overlap).
// ds redesign: GLDS stages raw fp32 key/value rows (async, no VGPRs, per-lane
// scattered source) into linear LDS; transpose+cvt moved to LDS-read side.
// W staged cooperatively fp32->bf16 LDS per phase. 4 phases, 2 barriers each.
__global__ __launch_bounds__(256) void prepds_k(
    const float* __restrict__ Wq, const float* __restrict__ Wk,
    const float* __restrict__ Wv, const float* __restrict__ Wout,
    const float* __restrict__ query,
    const float* __restrict__ W_kds, const float* __restrict__ W_vds,
    const float* __restrict__ b0, const float* __restrict__ b1,
    const float* __restrict__ b2, const float* __restrict__ b3,
    const float* __restrict__ key, const float* __restrict__ value,
    u16* __restrict__ WT, u16* __restrict__ q_bf,
    u16* __restrict__ dstB, u16* __restrict__ key_ds)
{
  __shared__ char sm[50176];   // ds: Sg f32[128][64] (32KB) + Wbf u16[64][136] (17KB)
  const int blk = blockIdx.x;
  const int t = threadIdx.x;

  if (blk % 10 == 0) {
    // ---- downsample block: M=64(kds) x N=64(d-tile) x K=512(s) ----
    const int id = blk / 10;                 // [0,768)
    float* Sg = (float*)sm;                  // [128][64] f32, linear (GLDS dest)
    u16* Wbf = (u16*)(sm + 32768);           // [64][136] bf16
    const int nt = (id % 12) * 64;
    const int yb = id / 12;
    const int pair = yb >> 5, b = yb & 31;
    const float* src = (pair ? value : key) + (size_t)b * 512 * 768;
    const float* W32 = pair ? W_vds : W_kds;
    u16* dst = key_ds + (size_t)pair * 1572864 + (size_t)b * 49152;
    const int wave = t >> 6, lane = t & 63;
    const int wm = (wave >> 1) * 32, wn = (wave & 1) * 32;
    const int lrow = lane & 15, quad = lane >> 4;
    const int gr = lane >> 4;                // GLDS: row within 4-row group
    const int gc = (lane & 15) * 16;         // GLDS: byte offset within 256B row
    const int wrow = t >> 5;                 // W coop load: +i*8
    const int wcol = (t & 31) * 4;
    f32x4 acc[2][2] = {};

    for (int ph = 0; ph < 4; ++ph) {
      const int kb = ph * 128;
      // async-stage B: 8 GLDS per wave, each covers 4 rows x 256B
      #pragma unroll
      for (int j = 0; j < 8; ++j) {
        const int idx = wave * 8 + j;
        const float* gsrc = src + (size_t)(kb + idx * 4 + gr) * 768 + nt;
        GLDS16((const char*)gsrc + gc, (char*)Sg + idx * 1024);
      }
      // cooperative W stage: 8 independent f32x4 loads, cvt, LDS store
      f32x4 wr[8];
      #pragma unroll
      for (int i = 0; i < 8; ++i)
        wr[i] = *(const f32x4*)&W32[(size_t)(i * 8 + wrow) * 512 + kb + wcol];
      #pragma unroll
      for (int i = 0; i < 8; ++i) {
        u16x4 wv4;
        #pragma unroll
        for (int q2 = 0; q2 < 4; ++q2) wv4[q2] = f2bf(wr[i][q2]);
        *(u16x4*)&Wbf[(i * 8 + wrow) * 136 + wcol] = wv4;
      }
      __syncthreads();   // drains GLDS vmcnt + lgkm: Sg & Wbf ready
      #pragma unroll
      for (int s = 0; s < 4; ++s) {
        bf16x8 av[2], bv[2];
        #pragma unroll
        for (int i = 0; i < 2; ++i)
          av[i] = *(const bf16x8*)&Wbf[(wm + i * 16 + lrow) * 136 + s * 32 + quad * 8];
        #pragma unroll
        for (int j = 0; j < 2; ++j) {
          const int n2 = wn + j * 16 + lrow;
          u16x8 bb;
          #pragma unroll
          for (int e = 0; e < 8; ++e) bb[e] = f2bf(Sg[(s * 32 + quad * 8 + e) * 64 + n2]);
          bv[j] = *(bf16x8*)&bb;
        }
        #pragma unroll
        for (int i = 0; i < 2; ++i)
          #pragma unroll
          for (int j = 0; j < 2; ++j)
            acc[i][j] = __builtin_amdgcn_mfma_f32_16x16x32_bf16(av[i], bv[j], acc[i][j], 0, 0, 0);
      }
      __syncthreads();   // Sg/Wbf consumption complete before next phase GLDS
    }
    #pragma unroll
    for (int i = 0; i < 2; ++i)
      #pragma unroll
      for (int j = 0; j < 2; ++j) {
        const int col = nt + wn + j * 16 + lrow;
        #pragma unroll
        for (int r = 0; r < 4; ++r) {
          const int row = wm + i * 16 + quad * 4 + r;
          dst[(size_t)row * 768 + col] = f2bf(acc[i][j][r]);
        }
      }
    return;
  }

  const int pid = blk - blk / 10 - 1;        // [0, 6912)
  if (pid < 576) {
    // ---- weight transpose ----
    u16 (*T)[72] = (u16(*)[72])sm;
    const int bz = pid / 144, rr = pid % 144;
    const int r0 = (rr / 12) * 64, c0 = (rr % 12) * 64;
    const float* W = (bz == 0) ? Wq : (bz == 1) ? Wk : (bz == 2) ? Wv : Wout;
    u16* O = WT + (size_t)bz * 768 * 768;
    #pragma unroll
    for (int p = 0; p < 2; ++p) {
      int v = t + p * 256;
      int r = v / 8, c = (v % 8) * 8;
      f32x4 x0 = *(const f32x4*)&W[(size_t)(r0 + r) * 768 + c0 + c];
      f32x4 x1 = *(const f32x4*)&W[(size_t)(r0 + r) * 768 + c0 + c + 4];
      #pragma unroll
      for (int i = 0; i < 4; ++i) { T[r][c + i] = f2bf(x0[i]); T[r][c + 4 + i] = f2bf(x1[i]); }
    }
    __syncthreads();
    #pragma unroll
    for (int p = 0; p < 2; ++p) {
      int v = t + p * 256;
      int r = v / 8, c = (v % 8) * 8;
      u16x8 tv;
      #pragma unroll
      for (int i = 0; i < 8; ++i) tv[i] = T[c + i][r];
      *(u16x8*)&O[(size_t)(c0 + r) * 768 + r0 + c] = tv;
    }
  } else if (pid < 6720) {
    // ---- query fp32 -> bf16 ----
    const size_t i = (size_t)(pid - 576) * 256 + t;   // 6144*256 slots, *8 = 12582912
    f32x4 a = *(const f32x4*)&query[i * 8];
    f32x4 b = *(const f32x4*)&query[i * 8 + 4];
    u16x8 w;
    #pragma unroll
    for (int j = 0; j < 4; ++j) { w[j] = f2bf(a[j]); w[4 + j] = f2bf(b[j]); }
    *(u16x8*)&q_bf[i * 8] = w;
  } else if (pid < 6732) {
    // ---- bias converts: 3072 elements ----
    const int i = (pid - 6720) * 256 + t;
    if (i < 3072) {
      int s = i / 768, si = i % 768;
      const float* src = (s == 0) ? b0 : (s == 1) ? b1 : (s == 2) ? b2 : b3;
      dstB[i] = f2bf(src[si]);
    }
  }
}

// ---------------- fused phi_k/vals GEMM + KV-state ----------------
// grid 384 = (b,n). Per block: P = elu(key_ds[b]@WkT[n]+bk)+1, V = val_ds[b]@WvT[n]+bv
// (waves 0,2 = P rows; 1,3 = V rows), transposed to LDS, then sT[h][d] = P^T.. V
// in one 64x64x64 MFMA pass + z row-sums. Kills the phi_k/vals HBM round-trip.
__global__ __launch_bounds__(256) void fkv_k(
    const u16* __restrict__ key_ds,   // [2][32][64][768] bf16
    const u16* __restrict__ WT,       // WkT at +768^2, WvT at +2*768^2
    const u16* __restrict__ bias_c,   // bk at +768, bv at +1536
    u16* __restrict__ sT, float* __restrict__ z)
{
  __shared__ char sm[32768];
  u16* T0 = (u16*)sm;                 // 4 stage tiles [64][64] bf16, chunk-swizzled
  u16* Pt = (u16*)sm;                 // overlay after GEMM: [64][72]
  u16* Vt = (u16*)(sm + 9216);        // [64][72]
  const int x = blockIdx.x;           // b*12 + n
  const int b = x / 12, n = x % 12;
  const int t = threadIdx.x, wave = t >> 6, lane = t & 63;
  const u16* srcs[4] = {
    key_ds + (size_t)b * 49152,                       // A1 = key_ds[b]
    WT + 589824 + (size_t)n * 49152,                  // B1 = WkT rows n*64..
    key_ds + 1572864 + (size_t)b * 49152,             // A2 = val_ds[b]
    WT + 2 * 589824 + (size_t)n * 49152 };            // B2 = WvT rows n*64..
  const int grow = lane >> 3;                         // row in 8-row GLDS group
  const int gchunk = (lane & 7) ^ (grow & 7);         // source chunk swizzle
  const int isV = wave & 1;
  const int wm = (wave >> 1) * 32;                    // k-rows
  const u16* Atile_s = srcs[isV ? 2 : 0];
  (void)Atile_s;
  const u16* Asrc = srcs[isV ? 2 : 0];
  const u16* Bsrc = srcs[isV ? 3 : 1];
  (void)Asrc; (void)Bsrc;
  u16* Atile = T0 + (isV ? 2 : 0) * 4096;
  u16* Btile = T0 + (isV ? 3 : 1) * 4096;
  const int lrow = lane & 15, quad = lane >> 4;
  f32x4 acc[2][4] = {};

  for (int k0 = 0; k0 < 768; k0 += 64) {
    // stage: wave w loads tile w (8 GLDS x 1KB, 8 rows each, chunk-swizzled src)
    const u16* s = srcs[wave];
    u16* dtile = T0 + wave * 4096;
    #pragma unroll
    for (int j = 0; j < 8; ++j) {
      const u16* gsrc = s + (size_t)(j * 8 + grow) * 768 + k0 + gchunk * 8;
      GLDS16(gsrc, (char*)dtile + j * 1024);
    }
    __syncthreads();
    #pragma unroll
    for (int c = 0; c < 2; ++c) {
      bf16x8 av[2], bv[4];
      #pragma unroll
      for (int i = 0; i < 2; ++i) {
        const int row = wm + i * 16 + lrow;
        av[i] = *(const bf16x8*)&Atile[row * 64 + (((c * 4 + quad) ^ (row & 7)) * 8)];
      }
      #pragma unroll
      for (int j = 0; j < 4; ++j) {
        const int row = j * 16 + lrow;
        bv[j] = *(const bf16x8*)&Btile[row * 64 + (((c * 4 + quad) ^ (row & 7)) * 8)];
      }
      #pragma unroll
      for (int i = 0; i < 2; ++i)
        #pragma unroll
        for (int j = 0; j < 4; ++j)
          acc[i][j] = __builtin_amdgcn_mfma_f32_16x16x32_bf16(av[i], bv[j], acc[i][j], 0, 0, 0);
    }
    __syncthreads();
  }

  // epilogue: bias (+elu+1 for P), write TRANSPOSED tiles Pt[d][k], Vt[h][k]
  const u16* bias = bias_c + (isV ? 1536 : 768) + n * 64;
  u16* Ttile = isV ? Vt : Pt;
  #pragma unroll
  for (int i = 0; i < 2; ++i)
    #pragma unroll
    for (int j = 0; j < 4; ++j) {
      const int col = j * 16 + lrow;                 // d (P) or h (V)
      const float badd = bf2f(bias[col]);
      u16x4 pk4;
      #pragma unroll
      for (int r = 0; r < 4; ++r) {
        float v = acc[i][j][r] + badd;
        if (!isV) v = v > 0.0f ? v + 1.0f : __expf(v);
        pk4[r] = f2bf(v);
      }
      *(u16x4*)&Ttile[col * 72 + wm + i * 16 + quad * 4] = pk4;
    }
  __syncthreads();

  // sT[h][d] = sum_k V[k][h] * P[k][d]  (A' = Vt rows h, B' = Pt rows d, K=64)
  const int wm2 = (wave >> 1) * 32, wn2 = (wave & 1) * 32;
  f32x4 a2[2][2] = {};
  #pragma unroll
  for (int c = 0; c < 2; ++c) {
    bf16x8 av[2], bv[2];
    #pragma unroll
    for (int i = 0; i < 2; ++i)
      av[i] = *(const bf16x8*)&Vt[(wm2 + i * 16 + lrow) * 72 + c * 32 + quad * 8];
    #pragma unroll
    for (int j = 0; j < 2; ++j)
      bv[j] = *(const bf16x8*)&Pt[(wn2 + j * 16 + lrow) * 72 + c * 32 + quad * 8];
    #pragma unroll
    for (int i = 0; i < 2; ++i)
      #pragma unroll
      for (int j = 0; j < 2; ++j)
        a2[i][j] = __builtin_amdgcn_mfma_f32_16x16x32_bf16(av[i], bv[j], a2[i][j], 0, 0, 0);
  }
  u16* sTg = sT + (size_t)x * 4096;
  #pragma unroll
  for (int i = 0; i < 2; ++i)
    #pragma unroll
    for (int j = 0; j < 2; ++j)
      #pragma unroll
      for (int r = 0; r < 4; ++r)
        sTg[(size_t)(wm2 + i * 16 + quad * 4 + r) * 64 + wn2 + j * 16 + lrow] = f2bf(a2[i][j][r]);
  // z[d] = sum_k P[k][d] = row-sum of Pt
  if (t < 64) {
    float zz = 0.f;
    #pragma unroll
    for (int g = 0; g < 8; ++g) {
      u16x8 p = *(const u16x8*)&Pt[t * 72 + g * 8];
      #pragma unroll
      for (int e = 0; e < 8; ++e) zz += bf2f(p[e]);
    }
    z[(size_t)x * 64 + t] = zz;
  }
}

// ---------------- m97-style GEMM: bf16 A[M,K] x Bt[N,K] -> C, global_load_lds ----------------
template<int ACT, bool OF32>
__global__ __launch_bounds__(256) void gemm97_k(
    const u16* __restrict__ A, int lda,
    const u16* __restrict__ Bt, int ldb,
    void* __restrict__ Craw, int ldc,
    const u16* __restrict__ bias, int K)
{
  __shared__ u16 As[128 * 32];   // unpadded: GLDS needs contiguous lane order
  __shared__ u16 Bs[128 * 32];
  const int mt = blockIdx.x * 128, nt = blockIdx.y * 128;
  const int t = threadIdx.x, wave = t >> 6, lane = t & 63;
  const int wm = (wave >> 1) * 64, wn = (wave & 1) * 64;
  const int lrow = lane & 15, quad = lane >> 4;
  f32x4 acc[4][4] = {};

  for (int k0 = 0; k0 < K; k0 += 32) {
    __syncthreads();
    #pragma unroll
    for (int p = 0; p < 2; ++p) {
      const int s = wave * 128 + p * 64 + lane;
      const int r = s >> 2, c = (s & 3) * 8;
      const int lb = (wave * 128 + p * 64) * 8;
      GLDS16(&A[(size_t)(mt + r) * lda + k0 + c], &As[lb]);
      GLDS16(&Bt[(size_t)(nt + r) * ldb + k0 + c], &Bs[lb]);
    }
    __syncthreads();

    bf16x8 av[4], bv[4];
    #pragma unroll
    for (int i = 0; i < 4; ++i) av[i] = *(const bf16x8*)&As[(wm + i * 16 + lrow) * 32 + quad * 8];
    #pragma unroll
    for (int j = 0; j < 4; ++j) bv[j] = *(const bf16x8*)&Bs[(wn + j * 16 + lrow) * 32 + quad * 8];
    #pragma unroll
    for (int i = 0; i < 4; ++i)
      #pragma unroll
      for (int j = 0; j < 4; ++j)
        acc[i][j] = __builtin_amdgcn_mfma_f32_16x16x32_bf16(av[i], bv[j], acc[i][j], 0, 0, 0);
  }

  #pragma unroll
  for (int i = 0; i < 4; ++i) {
    #pragma unroll
    for (int j = 0; j < 4; ++j) {
      const int col = nt + wn + j * 16 + lrow;
      const float badd = bias ? bf2f(bias[col]) : 0.0f;
      #pragma unroll
      for (int r = 0; r < 4; ++r) {
        const int row = mt + wm + i * 16 + quad * 4 + r;
        float v = acc[i][j][r] + badd;
        if constexpr (ACT == 1) v = v > 0.0f ? v + 1.0f : __expf(v);
        if constexpr (OF32) ((float*)Craw)[(size_t)row * ldc + col] = v;
        else                ((u16*)Craw)[(size_t)row * ldc + col] = f2bf(v);
      }
    }
  }
}

// ---------------- a_v = (phi_q @ s) / (phi_q . z + eps), fused qz, in-place ----------------
__global__ __launch_bounds__(256) void attn_av_k(
    u16* __restrict__ phi_q, const u16* __restrict__ sT, const float* __restrict__ zbuf)
{
  __shared__ u16 As[64 * 72];
  __shared__ u16 Bs[64 * 72];
  __shared__ float zv[64];
  __shared__ float zpart[4][64];
  __shared__ float zq[64];
  const int x = blockIdx.x, y = blockIdx.y;
  const int b = y / 12, n = y % 12;
  const int t = threadIdx.x;
  u16* Abase = phi_q + (size_t)b * 512 * 768 + (size_t)x * 64 * 768 + n * 64;
  const u16* Bbase = sT + (size_t)y * 4096;
  if (t < 64) zv[t] = zbuf[(size_t)y * 64 + t];
  #pragma unroll
  for (int p = 0; p < 2; ++p) {
    int v = t + p * 256;
    int r = v >> 3, c = (v & 7) * 8;
    *(u16x8*)&As[r * 72 + c] = *(const u16x8*)&Abase[(size_t)r * 768 + c];
    *(u16x8*)&Bs[r * 72 + c] = *(const u16x8*)&Bbase[r * 64 + c];
  }
  __syncthreads();
  {
    int r = t & 63, seg = t >> 6;
    float s = 0.f;
    #pragma unroll
    for (int j = 0; j < 16; ++j) s += bf2f(As[r * 72 + seg * 16 + j]) * zv[seg * 16 + j];
    zpart[seg][r] = s;
  }
  __syncthreads();
  if (t < 64) {
    float s = zpart[0][t] + zpart[1][t] + zpart[2][t] + zpart[3][t];
    zq[t] = 1.0f / (s + 1e-6f);
  }
  const int wave = t >> 6, lane = t & 63;
  const int wm = (wave >> 1) * 32, wn = (wave & 1) * 32;
  const int lrow = lane & 15, quad = lane >> 4;
  f32x4 acc[2][2] = {};
  #pragma unroll
  for (int c = 0; c < 2; ++c) {
    bf16x8 av[2], bv[2];
    #pragma unroll
    for (int i = 0; i < 2; ++i) av[i] = *(const bf16x8*)&As[(wm + i * 16 + lrow) * 72 + c * 32 + quad * 8];
    #pragma unroll
    for (int j = 0; j < 2; ++j) bv[j] = *(const bf16x8*)&Bs[(wn + j * 16 + lrow) * 72 + c * 32 + quad * 8];
    #pragma unroll
    for (int i = 0; i < 2; ++i)
      #pragma unroll
      for (int j = 0; j < 2; ++j)
        acc[i][j] = __builtin_amdgcn_mfma_f32_16x16x32_bf16(av[i], bv[j], acc[i][j], 0, 0, 0);
  }
  __syncthreads();
  #pragma unroll
  for (int i = 0; i < 2; ++i)
    #pragma unroll
    for (int j = 0; j < 2; ++j) {
      const int col = wn + j * 16 + lrow;
      #pragma unroll
      for (int r = 0; r < 4; ++r) {
        const int row = wm + i * 16 + quad * 4 + r;
        Abase[(size_t)row * 768 + col] = f2bf(acc[i][j][r] * zq[row]);
      }
    }
}

__global__ void tagfill_k(float* out, float val, int n) {
  int i = blockIdx.x * 256 + threadIdx.x;
  if (i < n) out[i] = val;
}

extern "C" void kernel_launch(void* const* d_in, const int* in_sizes, int n_in,
                              void* d_out, int out_size, void* d_ws, size_t ws_size,
                              hipStream_t stream) {
  (void)out_size;
  float* out = (float*)d_out;

  int o;
  if (n_in >= 14 && in_sizes[3] == 1) o = 4;
  else if (n_in == 13) o = 3;
  else { tagfill_k<<<4, 256, 0, stream>>>(out, 77.0f, 1024); return; }
  if (in_sizes[0] != 12582912 || in_sizes[o + 0] != 32768 || in_sizes[o + 2] != 589824) {
    tagfill_k<<<4, 256, 0, stream>>>(out, 88.0f, 1024); return;
  }

  const float* query = (const float*)d_in[0];
  const float* key   = (const float*)d_in[1];
  const float* value = (const float*)d_in[2];
  const float* W_kds = (const float*)d_in[o + 0];
  const float* W_vds = (const float*)d_in[o + 1];
  const float* Wq   = (const float*)d_in[o + 2];
  const float* bq   = (const float*)d_in[o + 3];
  const float* Wk   = (const float*)d_in[o + 4];
  const float* bk   = (const float*)d_in[o + 5];
  const float* Wv   = (const float*)d_in[o + 6];
  const float* bv   = (const float*)d_in[o + 7];
  const float* Wout = (const float*)d_in[o + 8];
  const float* bout = (const float*)d_in[o + 9];

  const size_t NEED = 61478912;
  if (ws_size < NEED) { tagfill_k<<<4, 256, 0, stream>>>(out, 123.0f, 1024); return; }

  char* base = (char*)d_ws;
  u16*   WT     = (u16*)base;                         // 4,718,592
  char*  Breg   = base + 4718592;                     // 25,165,824 region
  u16*   q_bf   = (u16*)Breg;                         // dies after phi_q GEMM
  u16*   sT     = (u16*)Breg;                         // then sT (over q_bf, dead)
  float* zbuf   = (float*)(Breg + 3145728);           // over dead q_bf
  u16*   phi_q  = (u16*)(base + 29884416);            // 25,165,824
  u16*   bias_c = (u16*)(base + 55181312);            // 6,144
  u16*   key_ds = (u16*)(base + 55187456);            // 6,291,456
  u16* a_v = phi_q;
  u16* WqT   = WT;
  u16* WoutT = WT + 3 * 768 * 768;
  u16* bq_c = bias_c, *bout_c = bias_c + 2304;

  // 1. fused prep + downsample, ds interleaved 1-in-10
  prepds_k<<<7680, 256, 0, stream>>>(Wq, Wk, Wv, Wout, query, W_kds, W_vds,
                                     bq, bk, bv, bout, key, value,
                                     WT, q_bf, bias_c, key_ds);

  // 2. phi_q = elu(q_bf @ Wq + bq) + 1
  gemm97_k<1, false><<<dim3(128, 6), 256, 0, stream>>>(
      q_bf, 768, WqT, 768, phi_q, 768, bq_c, 768);

  // 3. fused phi_k/vals + KV state (sT/zbuf overwrite q_bf — dead after step 2)
  fkv_k<<<384, 256, 0, stream>>>(key_ds, WT, bias_c, sT, zbuf);

  // 4. a_v = (phi_q @ s) * 1/(phi_q.z+eps), fused qz, in-place
  attn_av_k<<<dim3(8, 384), 256, 0, stream>>>(phi_q, sT, zbuf);

  // 5. out = a_v @ Wout + bout (fp32 C)
  gemm97_k<0, true><<<dim3(128, 6), 256, 0, stream>>>(
      a_v, 768, WoutT, 768, out, 768, bout_c, 768);
}